// Round 6
// baseline (812.048 us; speedup 1.0000x reference)
//
#include <hip/hip_runtime.h>
#include <hip/hip_bf16.h>

// SpatialContextNet on MI355X (gfx950). Round 9.
// corr ROLE DELETED: transpose blocks (b, kt=64ch, mt=row y) already stage
// corr's center row [64ch][64x] in LDS. Each tile block now also:
//   - issues 4 vertical row loads per channel (8 ch/thread, coalesced)
//     BEFORE the existing barrier,
//   - computes the 25 shift-partials from regs (vertical) + LDS (horizontal),
//   - reduces across waves via LDS atomicAdd into rbuf[25][64],
//   - drains <=4 global atomics/thread into corr (16 adds/addr over kt).
// The 512-block latency-bound corr tail (R4..R8's ~90us critical path)
// becomes a balanced +25% increment on 8192 streaming blocks.
// wcast role moved to the FRONT of the grid (no tail). memset/reduce2/gemm
// frozen from R8 (gemm = verified 93us R4 kernel).
//
// feature [8,1024,64,64] f32, conv_w [1024,1049] f32, conv_b [1024] f32.
// Out [8,1024,64,64] f32.

typedef __attribute__((ext_vector_type(8))) short short8x;
typedef __attribute__((ext_vector_type(4))) float floatx4;

#define B_   8
#define C_   1024
#define HW_  4096
#define KPAD 1088
#define NT   17
#define NWC  272   // wcast blocks: 272*4096 = 1024*1088 exactly

__device__ __forceinline__ unsigned short f2bf(float f) {
  unsigned int u = __float_as_uint(f);
  u += 0x7FFFu + ((u >> 16) & 1u);
  return (unsigned short)(u >> 16);
}

__device__ __forceinline__ void async16(const void* g, void* l) {
  __builtin_amdgcn_global_load_lds(
      (__attribute__((address_space(1))) void*)(void*)g,
      (__attribute__((address_space(3))) void*)l, 16, 0, 0);
}

__device__ __forceinline__ short8x rd16(const char* p) {
  return *(const short8x*)p;
}

// ---- K1: merged aux: wcast + {transpose-cast + corr partials} per tile -----
// grid 8464 x 512. n<272: wcast. n>=272: tile t=n-272 of 8192 =
// b(8) x kt(16 ch-tiles) x mt(64 rows): t = ((b*16)+kt)*64 + mt.
__global__ __launch_bounds__(512) void scn_aux(
    const float* __restrict__ f, float* __restrict__ corr,
    unsigned short* __restrict__ At, const float* __restrict__ w,
    unsigned short* __restrict__ Wb) {
  __shared__ float lds2[64][65];     // [k_local][x] staged center rows
  __shared__ float rbuf[25][64];     // per-block corr partials (j, x)
  const int n = blockIdx.x;
  const int tid = threadIdx.x;

  if (n < NWC) {
    // ================= wcast role: conv_w f32 -> Wb bf16, pad to 1088 ======
    const int base = n * 4096 + tid * 8;
    const int o = base / KPAD, kk = base - o * KPAD;
    short8x v;
#pragma unroll
    for (int e = 0; e < 8; ++e) {
      const int k = kk + e;
      v[e] = (k < 1049) ? (short)f2bf(w[(size_t)o * 1049 + k]) : (short)0;
    }
    *(short8x*)(Wb + (size_t)o * KPAD + kk) = v;
    return;
  }

  // ================= tile role =============================================
  const int t = n - NWC;
  const int mt = t & 63;            // row y
  const int kt = (t >> 6) & 15;     // 64-channel tile
  const int b  = t >> 10;
  const int y  = mt;

  // zero the reduce buffer (visible after sync1)
#pragma unroll
  for (int z = tid; z < 1600; z += 512) ((float*)rbuf)[z] = 0.f;

  // ---- stage center rows: lds2[k][x] = f[b][kt*64+k][y][x] (float4) ----
  const int m4 = (tid & 15) << 2, kr0 = tid >> 4;  // kr0 0..31
  const float* src = f + ((size_t)b * C_ + kt * 64 + kr0) * HW_ + y * 64 + m4;
#pragma unroll
  for (int i = 0; i < 2; ++i) {
    floatx4 v = *(const floatx4*)(src + (size_t)i * 32 * HW_);
    float* d = &lds2[kr0 + i * 32][m4];
    d[0] = v[0]; d[1] = v[1]; d[2] = v[2]; d[3] = v[3];
  }

  // ---- vertical neighbor loads (independent of LDS; land by sync1) ----
  const int x = tid & 63, g = tid >> 6;            // 8 ch per thread
  const bool ym2 = (y >= 2), ym1 = (y >= 1), yp1 = (y <= 62), yp2 = (y <= 61);
  const float* fbase = f + ((size_t)b * C_ + kt * 64 + g * 8) * HW_ + y * 64 + x;
  float vm2[8], vm1[8], vp1[8], vp2[8];
#pragma unroll
  for (int cc = 0; cc < 8; ++cc) {
    const float* rp = fbase + (size_t)cc * HW_;
    vm2[cc] = ym2 ? rp[-128] : 0.f;
    vm1[cc] = ym1 ? rp[-64] : 0.f;
    vp1[cc] = yp1 ? rp[64] : 0.f;
    vp2[cc] = yp2 ? rp[128] : 0.f;
  }

  __syncthreads();

  // ---- At center write: At[b][y*64+x'][kt*64 + c*8 + j] ----
  {
    const int c = tid & 7, mr = tid >> 3;
    unsigned short* dst =
        At + ((size_t)b * HW_ + mt * 64 + mr) * KPAD + kt * 64 + c * 8;
    short8x v;
#pragma unroll
    for (int j = 0; j < 8; ++j) v[j] = (short)f2bf(lds2[c * 8 + j][mr]);
    *(short8x*)dst = v;
  }

  // ---- corr partials: h[dxi*5+dyi] = sum_c v[dyi]*ccv[dxi] ----
  const int xs0 = (x + 2 < 64) ? x + 2 : 63;
  const int xs1 = (x + 1 < 64) ? x + 1 : 63;
  const int xs3 = (x - 1 >= 0) ? x - 1 : 0;
  const int xs4 = (x - 2 >= 0) ? x - 2 : 0;

  float h[25];
#pragma unroll
  for (int j = 0; j < 25; ++j) h[j] = 0.f;
#pragma unroll
  for (int cc = 0; cc < 8; ++cc) {
    const float* lr = &lds2[g * 8 + cc][0];
    const float ctr = lr[x];
    const float c0 = lr[xs0], c1 = lr[xs1], c3 = lr[xs3], c4 = lr[xs4];
    const float v[5] = {vm2[cc], vm1[cc], ctr, vp1[cc], vp2[cc]};
    const float ccv[5] = {c0, c1, ctr, c3, c4};
#pragma unroll
    for (int dxi = 0; dxi < 5; ++dxi)
#pragma unroll
      for (int dyi = 0; dyi < 5; ++dyi)
        h[dxi * 5 + dyi] = fmaf(v[dyi], ccv[dxi], h[dxi * 5 + dyi]);
  }

  // ---- cross-wave reduce: rbuf[j][x] += h[j] (8 waves per addr) ----
#pragma unroll
  for (int j = 0; j < 25; ++j) atomicAdd(&rbuf[j][x], h[j]);

  __syncthreads();

  // ---- drain: global atomics into corr, rotated target (skip OOB) ----
  float* cb = corr + b * HW_ + y * 64;
#pragma unroll
  for (int k = 0; k < 4; ++k) {
    const int v = tid + k * 512;
    if (v < 1600) {
      const int j = v >> 6, xx = v & 63;
      const int dx = (j / 5) - 2;
      const int tgt = xx - dx;
      if ((unsigned)tgt < 64u)
        atomicAdd(cb + (size_t)j * 32768 + tgt, ((float*)rbuf)[v]);
    }
  }
}

// ---- K2: reduce2 — invn from corr[12] halo (LDS) + At rows 1024..1087 ------
// grid (16, 8), block 256 (4 y-rows per block, 8-row invn halo in LDS).
__global__ __launch_bounds__(256) void scn_reduce2(
    const float* __restrict__ corr, unsigned short* __restrict__ At) {
  __shared__ float linv[8][64];
  const int b = blockIdx.y;
  const int bx = blockIdx.x;
  const int tid = threadIdx.x;
  const int x = tid & 63;
  const int y0 = bx * 4;

  const float* c12 = corr + (size_t)12 * 32768 + b * HW_;
#pragma unroll
  for (int rr = 0; rr < 2; ++rr) {
    const int rsel = (tid >> 6) + rr * 4;
    const int yy = y0 - 2 + rsel;
    const float s = (yy >= 0 && yy < 64) ? c12[yy * 64 + x] : 1.0f;
    linv[rsel][x] = 1.0f / fmaxf(sqrtf(s), 1e-12f);
  }
  __syncthreads();

  const int m = bx * 256 + tid;
  const int i = b * HW_ + m;
  const int yr = tid >> 6;
  const float ic = linv[yr + 2][x];

  unsigned short r[64];
#pragma unroll
  for (int j = 0; j < 25; ++j) {
    const float acc = corr[(size_t)j * 32768 + i];
    const int dy = (j % 5) - 2, dx = (j / 5) - 2;
    const int ny = y0 + yr + dy, nx = x + dx;
    const float in2 = (ny >= 0 && ny < 64 && nx >= 0 && nx < 64)
                          ? linv[yr + 2 + dy][nx] : 0.f;
    r[j] = f2bf(acc * ic * in2);
  }
#pragma unroll
  for (int j = 25; j < 64; ++j) r[j] = 0;
  unsigned short* row = At + ((size_t)b * HW_ + m) * KPAD + 1024;
#pragma unroll
  for (int v = 0; v < 8; ++v) *(short8x*)(row + v * 8) = *(short8x*)(r + v * 8);
}

// ---- K3: bf16 MFMA GEMM 256x256/BK=64, pipelined (exact Round-4 kernel) ----
// grid (16 nb, 4 ob, 8 b), block 512 (8 waves: wm = wid>>2, wn = wid&3).
// LDS 128 KiB: buf[2] x { A: 2 halves x [128][64] ; B: same }, bf16.
// Staging: global_load_lds, linear dest, inverse-swizzled global source.
// Read swizzle: 16B slot ^= (row&7). Counted vmcnt(8), raw s_barrier only.
__global__ __launch_bounds__(512, 2) void scn_gemm(
    const unsigned short* __restrict__ Wb, const unsigned short* __restrict__ At,
    const float* __restrict__ bias, float* __restrict__ out) {
  extern __shared__ char lds[];
  const int tid = threadIdx.x;
  const int l = tid & 63;
  const int wid = tid >> 6;
  const int wm = wid >> 2;
  const int wn = wid & 3;
  const int nb = blockIdx.x, ob = blockIdx.y, b = blockIdx.z;

  const int rr = tid >> 3;
  const int cswz = ((tid & 7) ^ (rr & 7)) << 3;
  const unsigned short* gA = Wb + (size_t)(ob * 256 + rr) * KPAD + cswz;
  const unsigned short* gB = At + ((size_t)b * HW_ + nb * 256 + rr) * KPAD + cswz;
  char* const dBase = (char*)lds + tid * 16;

#define ISSUE_A(bf, kt)                                         \
  do {                                                          \
    const unsigned short* _s = gA + (kt) * 64;                  \
    char* _d = dBase + (bf) * 65536;                            \
    async16(_s, _d);                                            \
    async16(_s + (size_t)64 * KPAD, _d + 8192);                 \
    async16(_s + (size_t)128 * KPAD, _d + 16384);               \
    async16(_s + (size_t)192 * KPAD, _d + 24576);               \
  } while (0)

#define ISSUE_B(bf, kt)                                         \
  do {                                                          \
    const unsigned short* _s = gB + (kt) * 64;                  \
    char* _d = dBase + (bf) * 65536 + 32768;                    \
    async16(_s, _d);                                            \
    async16(_s + (size_t)64 * KPAD, _d + 8192);                 \
    async16(_s + (size_t)128 * KPAD, _d + 16384);               \
    async16(_s + (size_t)192 * KPAD, _d + 24576);               \
  } while (0)

  const int l15 = l & 15, l4g = l >> 4, l7 = l & 7;
  const int aoff0 = l15 * 128 + ((l4g ^ l7) << 4);
  const int aoff1 = l15 * 128 + (((l4g + 4) ^ l7) << 4);
  const char* aB0 = (const char*)lds + wm * 16384;
  const char* bB0 = (const char*)lds + 32768 + (wn >> 1) * 16384 + (wn & 1) * 8192;

  floatx4 acc[8][4];
#pragma unroll
  for (int i = 0; i < 8; ++i)
#pragma unroll
    for (int j = 0; j < 4; ++j) acc[i][j] = (floatx4){0.f, 0.f, 0.f, 0.f};

  ISSUE_A(0, 0); ISSUE_B(0, 0);
  ISSUE_A(1, 1); ISSUE_B(1, 1);
  asm volatile("s_waitcnt vmcnt(8)" ::: "memory");
  __builtin_amdgcn_s_barrier();

  short8x a[4][2], b0[2][2], b1[2][2];

  for (int t = 0; t < NT; ++t) {
    const int bf = t & 1;
    const char* ab = aB0 + bf * 65536;
    const char* bb = bB0 + bf * 65536;
    const int t2 = (t < NT - 2) ? (t + 2) : 0;

    // ---- P1: read Aq0 + Bh0; MFMA Q00 ----
#pragma unroll
    for (int i = 0; i < 4; ++i) {
      a[i][0] = rd16(ab + i * 2048 + aoff0);
      a[i][1] = rd16(ab + i * 2048 + aoff1);
    }
#pragma unroll
    for (int j = 0; j < 2; ++j) {
      b0[j][0] = rd16(bb + j * 2048 + aoff0);
      b0[j][1] = rd16(bb + j * 2048 + aoff1);
    }
    __builtin_amdgcn_s_barrier();
    asm volatile("s_waitcnt lgkmcnt(0)" ::: "memory");
    __builtin_amdgcn_sched_barrier(0);
    __builtin_amdgcn_s_setprio(1);
#pragma unroll
    for (int i = 0; i < 4; ++i)
#pragma unroll
      for (int j = 0; j < 2; ++j) {
        acc[i][j] = __builtin_amdgcn_mfma_f32_16x16x32_bf16(a[i][0], b0[j][0], acc[i][j], 0, 0, 0);
        acc[i][j] = __builtin_amdgcn_mfma_f32_16x16x32_bf16(a[i][1], b0[j][1], acc[i][j], 0, 0, 0);
      }
    __builtin_amdgcn_s_setprio(0);
    __builtin_amdgcn_s_barrier();

    // ---- P2: read Bh1; MFMA Q01 ----
#pragma unroll
    for (int j = 0; j < 2; ++j) {
      b1[j][0] = rd16(bb + (2 + j) * 2048 + aoff0);
      b1[j][1] = rd16(bb + (2 + j) * 2048 + aoff1);
    }
    __builtin_amdgcn_s_barrier();
    asm volatile("s_waitcnt lgkmcnt(0)" ::: "memory");
    __builtin_amdgcn_sched_barrier(0);
    __builtin_amdgcn_s_setprio(1);
#pragma unroll
    for (int i = 0; i < 4; ++i)
#pragma unroll
      for (int j = 0; j < 2; ++j) {
        acc[i][2 + j] = __builtin_amdgcn_mfma_f32_16x16x32_bf16(a[i][0], b1[j][0], acc[i][2 + j], 0, 0, 0);
        acc[i][2 + j] = __builtin_amdgcn_mfma_f32_16x16x32_bf16(a[i][1], b1[j][1], acc[i][2 + j], 0, 0, 0);
      }
    __builtin_amdgcn_s_setprio(0);
    __builtin_amdgcn_s_barrier();

    // ---- P3: read Aq1; issue B(t+2); MFMA Q11 ----
#pragma unroll
    for (int i = 0; i < 4; ++i) {
      a[i][0] = rd16(ab + (4 + i) * 2048 + aoff0);
      a[i][1] = rd16(ab + (4 + i) * 2048 + aoff1);
    }
    ISSUE_B(bf, t2);
    __builtin_amdgcn_s_barrier();
    asm volatile("s_waitcnt lgkmcnt(0)" ::: "memory");
    __builtin_amdgcn_sched_barrier(0);
    __builtin_amdgcn_s_setprio(1);
#pragma unroll
    for (int i = 0; i < 4; ++i)
#pragma unroll
      for (int j = 0; j < 2; ++j) {
        acc[4 + i][2 + j] = __builtin_amdgcn_mfma_f32_16x16x32_bf16(a[i][0], b1[j][0], acc[4 + i][2 + j], 0, 0, 0);
        acc[4 + i][2 + j] = __builtin_amdgcn_mfma_f32_16x16x32_bf16(a[i][1], b1[j][1], acc[4 + i][2 + j], 0, 0, 0);
      }
    __builtin_amdgcn_s_setprio(0);
    __builtin_amdgcn_s_barrier();

    // ---- P4: issue A(t+2); MFMA Q10; counted vmcnt(8) ----
    ISSUE_A(bf, t2);
    __builtin_amdgcn_s_barrier();
    __builtin_amdgcn_s_setprio(1);
#pragma unroll
    for (int i = 0; i < 4; ++i)
#pragma unroll
      for (int j = 0; j < 2; ++j) {
        acc[4 + i][j] = __builtin_amdgcn_mfma_f32_16x16x32_bf16(a[i][0], b0[j][0], acc[4 + i][j], 0, 0, 0);
        acc[4 + i][j] = __builtin_amdgcn_mfma_f32_16x16x32_bf16(a[i][1], b0[j][1], acc[4 + i][j], 0, 0, 0);
      }
    __builtin_amdgcn_s_setprio(0);
    asm volatile("s_waitcnt vmcnt(8)" ::: "memory");
    __builtin_amdgcn_s_barrier();
  }
  asm volatile("s_waitcnt vmcnt(0)" ::: "memory");
#undef ISSUE_A
#undef ISSUE_B

  float* outb = out + (size_t)b * C_ * HW_;
#pragma unroll
  for (int i = 0; i < 8; ++i) {
    const int o0 = ob * 256 + wm * 128 + i * 16 + l4g * 4;
    float bs[4];
#pragma unroll
    for (int r = 0; r < 4; ++r) bs[r] = bias[o0 + r];
#pragma unroll
    for (int j = 0; j < 4; ++j) {
      const int m = nb * 256 + wn * 64 + j * 16 + l15;
#pragma unroll
      for (int r = 0; r < 4; ++r) {
        float v = acc[i][j][r] + bs[r];
        outb[(size_t)(o0 + r) * HW_ + m] = v > 0.f ? v : 0.f;
      }
    }
  }
}

// ---- launch ----------------------------------------------------------------
extern "C" void kernel_launch(void* const* d_in, const int* in_sizes, int n_in,
                              void* d_out, int out_size, void* d_ws, size_t ws_size,
                              hipStream_t stream) {
  const float* feature = (const float*)d_in[0];
  const float* conv_w  = (const float*)d_in[1];
  const float* conv_b  = (const float*)d_in[2];
  float* out = (float*)d_out;

  // workspace layout (bytes), total 76,808,192:
  //   At   [32768][1088] bf16 : 0          .. 71,303,168
  //   corr [25][32768] f32    : 71,303,168 .. 74,579,968  (memset each call)
  //   Wb   [1024][1088] bf16  : 74,579,968 .. 76,808,192
  char* ws = (char*)d_ws;
  unsigned short* At = (unsigned short*)(ws);
  float* corr        = (float*)(ws + 71303168);
  unsigned short* Wb = (unsigned short*)(ws + 74579968);

  static int gemm_attr_set = 0;
  if (!gemm_attr_set) {
    hipFuncSetAttribute((const void*)scn_gemm,
                        hipFuncAttributeMaxDynamicSharedMemorySize, 131072);
    gemm_attr_set = 1;
  }

  hipMemsetAsync(corr, 0, 25 * 32768 * sizeof(float), stream);
  // 8464 blocks: n<272 wcast; n>=272 -> tile (b, kt, mt) transpose+corr
  scn_aux<<<dim3(8464), 512, 0, stream>>>(feature, corr, At, conv_w, Wb);
  scn_reduce2<<<dim3(16, 8), 256, 0, stream>>>(corr, At);
  scn_gemm<<<dim3(16, 4, 8), 512, 131072, stream>>>(Wb, At, conv_b, out);
}

// Round 7
// 365.703 us; speedup vs baseline: 2.2205x; 2.2205x over previous
//
#include <hip/hip_runtime.h>
#include <hip/hip_bf16.h>

// SpatialContextNet on MI355X (gfx950). Round 10.
// R9 (per-tile corr) regressed 379->812: FETCH doubled (5x row re-fetch at
// 256B granularity, 796 GB/s) -> reverted to R8 wholesale. One change vs R8:
// corr role split 8->16 channel chunks (64 ch/block, 1024 blocks, 1:4
// interleave with transpose). Work/block halves, 4/CU co-residency, corr
// tail (R8's critical path inside aux) halves. Reads identical -> FETCH
// unchanged (~162MB). Global corr accumulation already atomic (16 adds/addr).
// memset / reduce2 / gemm: frozen R8 (gemm = verified 93us R4 kernel).
//
// feature [8,1024,64,64] f32, conv_w [1024,1049] f32, conv_b [1024] f32.
// Out [8,1024,64,64] f32.

typedef __attribute__((ext_vector_type(8))) short short8x;
typedef __attribute__((ext_vector_type(4))) float floatx4;

#define B_   8
#define C_   1024
#define HW_  4096
#define KPAD 1088
#define NT   17

__device__ __forceinline__ unsigned short f2bf(float f) {
  unsigned int u = __float_as_uint(f);
  u += 0x7FFFu + ((u >> 16) & 1u);
  return (unsigned short)(u >> 16);
}

__device__ __forceinline__ void async16(const void* g, void* l) {
  __builtin_amdgcn_global_load_lds(
      (__attribute__((address_space(1))) void*)(void*)g,
      (__attribute__((address_space(3))) void*)l, 16, 0, 0);
}

__device__ __forceinline__ short8x rd16(const char* p) {
  return *(const short8x*)p;
}

// ---- K1: merged aux: corr partials (atomic) + transpose-cast + wcast -------
// grid 5392 x 512. n<5120: n%5==0 -> corr block g=n/5 (1024 blocks, 64 ch);
// else transpose block (n/5)*4+(n%5-1) (4096 blocks, 2 tiles each).
// n>=5120: wcast (272 blocks, 8 elems/thread).
// corr: atomicAdd into corr[j*32768 + b*4096 + y*64 + wx] (rotated store).
__global__ __launch_bounds__(512) void scn_aux(
    const float* __restrict__ f, float* __restrict__ corr,
    unsigned short* __restrict__ At, const float* __restrict__ w,
    unsigned short* __restrict__ Wb) {
  __shared__ float lds2[2][64][65];
  const int n = blockIdx.x;
  const int tid = threadIdx.x;

  if (n >= 5120) {
    // ================= wcast role: conv_w f32 -> Wb bf16, pad to 1088 ======
    const int base = (n - 5120) * 4096 + tid * 8;
    const int o = base / KPAD, kk = base - o * KPAD;
    short8x v;
#pragma unroll
    for (int e = 0; e < 8; ++e) {
      const int k = kk + e;
      v[e] = (k < 1049) ? (short)f2bf(w[(size_t)o * 1049 + k]) : (short)0;
    }
    *(short8x*)(Wb + (size_t)o * KPAD + kk) = v;
    return;
  }

  const int g = n / 5, r = n - g * 5;
  if (r == 0) {
    // ================= corr role (R8 body, 64-ch chunks, 1024 blocks) ======
    const int x = tid & 63;
    const int y = (g & 7) * 8 + (tid >> 6);
    const int cs = (g >> 3) & 15, b = g >> 7;

    const int xs0 = (x + 2 < 64) ? x + 2 : 63;
    const int xs1 = (x + 1 < 64) ? x + 1 : 63;
    const int xs3 = (x - 1 >= 0) ? x - 1 : 0;
    const int xs4 = (x - 2 >= 0) ? x - 2 : 0;

    const bool ym2 = (y >= 2), ym1 = (y >= 1), yp1 = (y <= 62), yp2 = (y <= 61);

    const float* rp0 = f + ((size_t)b * C_ + cs * 64) * HW_ + y * 64;

    float h[25];
#pragma unroll
    for (int j = 0; j < 25; ++j) h[j] = 0.f;

#pragma unroll 4
    for (int c = 0; c < 64; ++c) {
      const float* rp = rp0 + (size_t)c * HW_;
      const float ctr = rp[x];
      const float vm2 = ym2 ? rp[x - 128] : 0.f;
      const float vm1 = ym1 ? rp[x - 64] : 0.f;
      const float vp1 = yp1 ? rp[x + 64] : 0.f;
      const float vp2 = yp2 ? rp[x + 128] : 0.f;
      const float c0 = __shfl(ctr, xs0, 64);
      const float c1 = __shfl(ctr, xs1, 64);
      const float c3 = __shfl(ctr, xs3, 64);
      const float c4 = __shfl(ctr, xs4, 64);
      const float v[5] = {vm2, vm1, ctr, vp1, vp2};
      const float cc[5] = {c0, c1, ctr, c3, c4};
#pragma unroll
      for (int dxi = 0; dxi < 5; ++dxi)
#pragma unroll
        for (int dyi = 0; dyi < 5; ++dyi)
          h[dxi * 5 + dyi] = fmaf(v[dyi], cc[dxi], h[dxi * 5 + dyi]);
    }

    float* pb = corr + b * HW_ + y * 64;
#pragma unroll
    for (int j = 0; j < 25; ++j) {
      const int dx = (j / 5) - 2;
      const int tgt = x - dx;
      const int wx = (tgt + 64) & 63;
      const float val = ((unsigned)tgt < 64u) ? h[j] : 0.f;
      atomicAdd(pb + (size_t)j * 32768 + wx, val);
    }
  } else {
    // ================= transpose role (float4 loads, 2 tiles/block) ========
    const int half = tid >> 8, t256 = tid & 255;
    const int tile = (g * 4 + (r - 1)) * 2 + half;
    const int b = tile >> 10, rem = tile & 1023;
    const int kt = rem >> 6, mt = rem & 63;

    const int m4 = (t256 & 15) << 2, kr0 = t256 >> 4;
    const float* src = f + ((size_t)b * C_ + kt * 64 + kr0) * HW_ + mt * 64 + m4;
#pragma unroll
    for (int i = 0; i < 4; ++i) {
      floatx4 v = *(const floatx4*)(src + (size_t)i * 16 * HW_);
      float* d = &lds2[half][kr0 + i * 16][m4];
      d[0] = v[0]; d[1] = v[1]; d[2] = v[2]; d[3] = v[3];
    }
    __syncthreads();
    unsigned short* dst = At + ((size_t)b * HW_ + mt * 64) * KPAD + kt * 64;
    const int c = t256 & 7, mr = t256 >> 3;
#pragma unroll
    for (int h2 = 0; h2 < 2; ++h2) {
      const int mm = mr + h2 * 32;
      short8x v;
#pragma unroll
      for (int j = 0; j < 8; ++j) v[j] = (short)f2bf(lds2[half][c * 8 + j][mm]);
      *(short8x*)(dst + (size_t)mm * KPAD + c * 8) = v;
    }
  }
}

// ---- K2: reduce2 — invn from corr[12] halo (LDS) + At rows 1024..1087 ------
// grid (16, 8), block 256 (4 y-rows per block, 8-row invn halo in LDS).
__global__ __launch_bounds__(256) void scn_reduce2(
    const float* __restrict__ corr, unsigned short* __restrict__ At) {
  __shared__ float linv[8][64];
  const int b = blockIdx.y;
  const int bx = blockIdx.x;
  const int tid = threadIdx.x;
  const int x = tid & 63;
  const int y0 = bx * 4;

  const float* c12 = corr + (size_t)12 * 32768 + b * HW_;
#pragma unroll
  for (int rr = 0; rr < 2; ++rr) {
    const int rsel = (tid >> 6) + rr * 4;
    const int yy = y0 - 2 + rsel;
    const float s = (yy >= 0 && yy < 64) ? c12[yy * 64 + x] : 1.0f;
    linv[rsel][x] = 1.0f / fmaxf(sqrtf(s), 1e-12f);
  }
  __syncthreads();

  const int m = bx * 256 + tid;
  const int i = b * HW_ + m;
  const int yr = tid >> 6;
  const float ic = linv[yr + 2][x];

  unsigned short r[64];
#pragma unroll
  for (int j = 0; j < 25; ++j) {
    const float acc = corr[(size_t)j * 32768 + i];
    const int dy = (j % 5) - 2, dx = (j / 5) - 2;
    const int ny = y0 + yr + dy, nx = x + dx;
    const float in2 = (ny >= 0 && ny < 64 && nx >= 0 && nx < 64)
                          ? linv[yr + 2 + dy][nx] : 0.f;
    r[j] = f2bf(acc * ic * in2);
  }
#pragma unroll
  for (int j = 25; j < 64; ++j) r[j] = 0;
  unsigned short* row = At + ((size_t)b * HW_ + m) * KPAD + 1024;
#pragma unroll
  for (int v = 0; v < 8; ++v) *(short8x*)(row + v * 8) = *(short8x*)(r + v * 8);
}

// ---- K3: bf16 MFMA GEMM 256x256/BK=64, pipelined (exact Round-4 kernel) ----
// grid (16 nb, 4 ob, 8 b), block 512 (8 waves: wm = wid>>2, wn = wid&3).
// LDS 128 KiB: buf[2] x { A: 2 halves x [128][64] ; B: same }, bf16.
// Staging: global_load_lds, linear dest, inverse-swizzled global source.
// Read swizzle: 16B slot ^= (row&7). Counted vmcnt(8), raw s_barrier only.
__global__ __launch_bounds__(512, 2) void scn_gemm(
    const unsigned short* __restrict__ Wb, const unsigned short* __restrict__ At,
    const float* __restrict__ bias, float* __restrict__ out) {
  extern __shared__ char lds[];
  const int tid = threadIdx.x;
  const int l = tid & 63;
  const int wid = tid >> 6;
  const int wm = wid >> 2;
  const int wn = wid & 3;
  const int nb = blockIdx.x, ob = blockIdx.y, b = blockIdx.z;

  const int rr = tid >> 3;
  const int cswz = ((tid & 7) ^ (rr & 7)) << 3;
  const unsigned short* gA = Wb + (size_t)(ob * 256 + rr) * KPAD + cswz;
  const unsigned short* gB = At + ((size_t)b * HW_ + nb * 256 + rr) * KPAD + cswz;
  char* const dBase = (char*)lds + tid * 16;

#define ISSUE_A(bf, kt)                                         \
  do {                                                          \
    const unsigned short* _s = gA + (kt) * 64;                  \
    char* _d = dBase + (bf) * 65536;                            \
    async16(_s, _d);                                            \
    async16(_s + (size_t)64 * KPAD, _d + 8192);                 \
    async16(_s + (size_t)128 * KPAD, _d + 16384);               \
    async16(_s + (size_t)192 * KPAD, _d + 24576);               \
  } while (0)

#define ISSUE_B(bf, kt)                                         \
  do {                                                          \
    const unsigned short* _s = gB + (kt) * 64;                  \
    char* _d = dBase + (bf) * 65536 + 32768;                    \
    async16(_s, _d);                                            \
    async16(_s + (size_t)64 * KPAD, _d + 8192);                 \
    async16(_s + (size_t)128 * KPAD, _d + 16384);               \
    async16(_s + (size_t)192 * KPAD, _d + 24576);               \
  } while (0)

  const int l15 = l & 15, l4g = l >> 4, l7 = l & 7;
  const int aoff0 = l15 * 128 + ((l4g ^ l7) << 4);
  const int aoff1 = l15 * 128 + (((l4g + 4) ^ l7) << 4);
  const char* aB0 = (const char*)lds + wm * 16384;
  const char* bB0 = (const char*)lds + 32768 + (wn >> 1) * 16384 + (wn & 1) * 8192;

  floatx4 acc[8][4];
#pragma unroll
  for (int i = 0; i < 8; ++i)
#pragma unroll
    for (int j = 0; j < 4; ++j) acc[i][j] = (floatx4){0.f, 0.f, 0.f, 0.f};

  ISSUE_A(0, 0); ISSUE_B(0, 0);
  ISSUE_A(1, 1); ISSUE_B(1, 1);
  asm volatile("s_waitcnt vmcnt(8)" ::: "memory");
  __builtin_amdgcn_s_barrier();

  short8x a[4][2], b0[2][2], b1[2][2];

  for (int t = 0; t < NT; ++t) {
    const int bf = t & 1;
    const char* ab = aB0 + bf * 65536;
    const char* bb = bB0 + bf * 65536;
    const int t2 = (t < NT - 2) ? (t + 2) : 0;

    // ---- P1: read Aq0 + Bh0; MFMA Q00 ----
#pragma unroll
    for (int i = 0; i < 4; ++i) {
      a[i][0] = rd16(ab + i * 2048 + aoff0);
      a[i][1] = rd16(ab + i * 2048 + aoff1);
    }
#pragma unroll
    for (int j = 0; j < 2; ++j) {
      b0[j][0] = rd16(bb + j * 2048 + aoff0);
      b0[j][1] = rd16(bb + j * 2048 + aoff1);
    }
    __builtin_amdgcn_s_barrier();
    asm volatile("s_waitcnt lgkmcnt(0)" ::: "memory");
    __builtin_amdgcn_sched_barrier(0);
    __builtin_amdgcn_s_setprio(1);
#pragma unroll
    for (int i = 0; i < 4; ++i)
#pragma unroll
      for (int j = 0; j < 2; ++j) {
        acc[i][j] = __builtin_amdgcn_mfma_f32_16x16x32_bf16(a[i][0], b0[j][0], acc[i][j], 0, 0, 0);
        acc[i][j] = __builtin_amdgcn_mfma_f32_16x16x32_bf16(a[i][1], b0[j][1], acc[i][j], 0, 0, 0);
      }
    __builtin_amdgcn_s_setprio(0);
    __builtin_amdgcn_s_barrier();

    // ---- P2: read Bh1; MFMA Q01 ----
#pragma unroll
    for (int j = 0; j < 2; ++j) {
      b1[j][0] = rd16(bb + (2 + j) * 2048 + aoff0);
      b1[j][1] = rd16(bb + (2 + j) * 2048 + aoff1);
    }
    __builtin_amdgcn_s_barrier();
    asm volatile("s_waitcnt lgkmcnt(0)" ::: "memory");
    __builtin_amdgcn_sched_barrier(0);
    __builtin_amdgcn_s_setprio(1);
#pragma unroll
    for (int i = 0; i < 4; ++i)
#pragma unroll
      for (int j = 0; j < 2; ++j) {
        acc[i][2 + j] = __builtin_amdgcn_mfma_f32_16x16x32_bf16(a[i][0], b1[j][0], acc[i][2 + j], 0, 0, 0);
        acc[i][2 + j] = __builtin_amdgcn_mfma_f32_16x16x32_bf16(a[i][1], b1[j][1], acc[i][2 + j], 0, 0, 0);
      }
    __builtin_amdgcn_s_setprio(0);
    __builtin_amdgcn_s_barrier();

    // ---- P3: read Aq1; issue B(t+2); MFMA Q11 ----
#pragma unroll
    for (int i = 0; i < 4; ++i) {
      a[i][0] = rd16(ab + (4 + i) * 2048 + aoff0);
      a[i][1] = rd16(ab + (4 + i) * 2048 + aoff1);
    }
    ISSUE_B(bf, t2);
    __builtin_amdgcn_s_barrier();
    asm volatile("s_waitcnt lgkmcnt(0)" ::: "memory");
    __builtin_amdgcn_sched_barrier(0);
    __builtin_amdgcn_s_setprio(1);
#pragma unroll
    for (int i = 0; i < 4; ++i)
#pragma unroll
      for (int j = 0; j < 2; ++j) {
        acc[4 + i][2 + j] = __builtin_amdgcn_mfma_f32_16x16x32_bf16(a[i][0], b1[j][0], acc[4 + i][2 + j], 0, 0, 0);
        acc[4 + i][2 + j] = __builtin_amdgcn_mfma_f32_16x16x32_bf16(a[i][1], b1[j][1], acc[4 + i][2 + j], 0, 0, 0);
      }
    __builtin_amdgcn_s_setprio(0);
    __builtin_amdgcn_s_barrier();

    // ---- P4: issue A(t+2); MFMA Q10; counted vmcnt(8) ----
    ISSUE_A(bf, t2);
    __builtin_amdgcn_s_barrier();
    __builtin_amdgcn_s_setprio(1);
#pragma unroll
    for (int i = 0; i < 4; ++i)
#pragma unroll
      for (int j = 0; j < 2; ++j) {
        acc[4 + i][j] = __builtin_amdgcn_mfma_f32_16x16x32_bf16(a[i][0], b0[j][0], acc[4 + i][j], 0, 0, 0);
        acc[4 + i][j] = __builtin_amdgcn_mfma_f32_16x16x32_bf16(a[i][1], b0[j][1], acc[4 + i][j], 0, 0, 0);
      }
    __builtin_amdgcn_s_setprio(0);
    asm volatile("s_waitcnt vmcnt(8)" ::: "memory");
    __builtin_amdgcn_s_barrier();
  }
  asm volatile("s_waitcnt vmcnt(0)" ::: "memory");
#undef ISSUE_A
#undef ISSUE_B

  float* outb = out + (size_t)b * C_ * HW_;
#pragma unroll
  for (int i = 0; i < 8; ++i) {
    const int o0 = ob * 256 + wm * 128 + i * 16 + l4g * 4;
    float bs[4];
#pragma unroll
    for (int r = 0; r < 4; ++r) bs[r] = bias[o0 + r];
#pragma unroll
    for (int j = 0; j < 4; ++j) {
      const int m = nb * 256 + wn * 64 + j * 16 + l15;
#pragma unroll
      for (int r = 0; r < 4; ++r) {
        float v = acc[i][j][r] + bs[r];
        outb[(size_t)(o0 + r) * HW_ + m] = v > 0.f ? v : 0.f;
      }
    }
  }
}

// ---- launch ----------------------------------------------------------------
extern "C" void kernel_launch(void* const* d_in, const int* in_sizes, int n_in,
                              void* d_out, int out_size, void* d_ws, size_t ws_size,
                              hipStream_t stream) {
  const float* feature = (const float*)d_in[0];
  const float* conv_w  = (const float*)d_in[1];
  const float* conv_b  = (const float*)d_in[2];
  float* out = (float*)d_out;

  // workspace layout (bytes), total 76,808,192:
  //   At   [32768][1088] bf16 : 0          .. 71,303,168
  //   corr [25][32768] f32    : 71,303,168 .. 74,579,968  (memset each call)
  //   Wb   [1024][1088] bf16  : 74,579,968 .. 76,808,192
  char* ws = (char*)d_ws;
  unsigned short* At = (unsigned short*)(ws);
  float* corr        = (float*)(ws + 71303168);
  unsigned short* Wb = (unsigned short*)(ws + 74579968);

  static int gemm_attr_set = 0;
  if (!gemm_attr_set) {
    hipFuncSetAttribute((const void*)scn_gemm,
                        hipFuncAttributeMaxDynamicSharedMemorySize, 131072);
    gemm_attr_set = 1;
  }

  hipMemsetAsync(corr, 0, 25 * 32768 * sizeof(float), stream);
  // 5392 blocks: n<5120 -> corr/transpose (1:4), n>=5120 -> wcast (272)
  scn_aux<<<dim3(5392), 512, 0, stream>>>(feature, corr, At, conv_w, Wb);
  scn_reduce2<<<dim3(16, 8), 256, 0, stream>>>(corr, At);
  scn_gemm<<<dim3(16, 4, 8), 512, 131072, stream>>>(Wb, At, conv_b, out);
}